// Round 9
// baseline (77.673 us; speedup 1.0000x reference)
//
#include <hip/hip_runtime.h>
#include <stdint.h>
#include <math.h>

// CategoricalSampler: argmax_v( logits[b,s,v]*(log2e/T) + g2(v) ), g2 = -log2(-log2 u),
// u from JAX threefry2x32-20 partitionable path: bits[i] = x0^x1, key=(0,42), ctr=(0, i).
// Bit-scheme verified R2; value path verified R3/R5/R6/R7/R8 (absmax=0).
//
// R4 lesson: direct __log2f(u) only — no cancellation forms.
// R8 lesson: compiler re-sinks source-level prefetch (VGPR stayed 16); memory is not
// the bottleneck. R9: the 1.6x dynamic/static multiplier = serial threefry dep chains
// (allocator serialized them into 16 VGPRs). Force 8 interleaved chains via batched
// arrays + __launch_bounds__(TPB,8); tournament argmax (group max + post-loop exact
// k-recovery) cuts 2.25 insts/elem.

constexpr int V = 128000;
constexpr int NROWS = 256;       // B*S
constexpr int TPB = 256;
constexpr int SPLITQ = 25;       // grid 6400 -> 8 blocks/CU; SEG=5120, J=5

__device__ __forceinline__ uint32_t rotl_(uint32_t x, uint32_t r) {
#if __has_builtin(__builtin_rotateleft32)
  return __builtin_rotateleft32(x, r);   // fshl -> single v_alignbit_b32
#else
  return (x << r) | (x >> (32u - r));
#endif
}

// Threefry-2x32-20 over N independent chains, round-interleaved for ILP.
// Input c[i] = ctr_i + 42 (ks1 pre-added). Output out[i] = x0 ^ x1 (inject5 folded).
// ks0=0, ks1=42, ks2=0x1BD11BDA^42=0x1BD11BF0. Sequence identical to R7 (verified).
#define TF_ROUND(r) \
  _Pragma("unroll") \
  for (int i = 0; i < N; ++i) { x0[i] += x1[i]; x1[i] = rotl_(x1[i], (r)) ^ x0[i]; }

template <int N>
__device__ __forceinline__ void threefry_xor_batch(const uint32_t* c, uint32_t* out) {
  uint32_t x0[N], x1[N];
#pragma unroll
  for (int i = 0; i < N; ++i) {          // round 1 (x0 = 0 + x1)
    x1[i] = c[i]; x0[i] = x1[i]; x1[i] = rotl_(x1[i], 13) ^ x0[i];
  }
  TF_ROUND(15) TF_ROUND(26) TF_ROUND(6)
#pragma unroll
  for (int i = 0; i < N; ++i) {          // inject1 (ks1 | ks2+1) + round 5
    x1[i] += 0x1BD11BF1u; x0[i] = x0[i] + 42u + x1[i]; x1[i] = rotl_(x1[i], 17) ^ x0[i];
  }
  TF_ROUND(29) TF_ROUND(16) TF_ROUND(24)
#pragma unroll
  for (int i = 0; i < N; ++i) {          // inject2 (ks2 | ks0+2) + round 9
    x1[i] += 2u; x0[i] = x0[i] + 0x1BD11BF0u + x1[i]; x1[i] = rotl_(x1[i], 13) ^ x0[i];
  }
  TF_ROUND(15) TF_ROUND(26) TF_ROUND(6)
#pragma unroll
  for (int i = 0; i < N; ++i) {          // inject3 (ks0=0 | ks1+3) + round 13
    x1[i] += 45u; x0[i] += x1[i]; x1[i] = rotl_(x1[i], 17) ^ x0[i];
  }
  TF_ROUND(29) TF_ROUND(16) TF_ROUND(24)
#pragma unroll
  for (int i = 0; i < N; ++i) {          // inject4 (ks1 | ks2+4) + round 17
    x1[i] += 0x1BD11BF4u; x0[i] = x0[i] + 42u + x1[i]; x1[i] = rotl_(x1[i], 13) ^ x0[i];
  }
  TF_ROUND(15) TF_ROUND(26) TF_ROUND(6)
#pragma unroll
  for (int i = 0; i < N; ++i) out[i] = (x0[i] + 0x1BD11BF0u) ^ (x1[i] + 5u);
}

__device__ __forceinline__ uint32_t mant_pack(uint32_t bits) {
#if __has_builtin(__builtin_amdgcn_alignbit)
  return __builtin_amdgcn_alignbit(127u, bits, 9u);  // (bits>>9)|0x3f800000
#else
  return (bits >> 9) | 0x3f800000u;
#endif
}

__device__ __forceinline__ float gval(uint32_t bits, float l, float scale) {
  const float u  = __uint_as_float(mant_pack(bits)) - 1.0f;  // [0,1); 0 -> -inf, loses
  const float s1 = __log2f(u);
  const float s2 = __log2f(-s1);          // g2 = -s2 (neg folds to VOP3 modifier)
  return fmaf(l, scale, -s2);
}

template <int SPLIT>
__global__ __launch_bounds__(TPB, 8) void CategoricalSampler_stage1(
    const float* __restrict__ logits, const float* __restrict__ temp,
    float2* __restrict__ ws) {
  constexpr int SEG = V / SPLIT;
  constexpr int J = SEG / (TPB * 4);   // exact by construction
  const int b   = blockIdx.x;
  const int row = b / SPLIT;           // block-uniform -> scalar ops
  const int seg = b - row * SPLIT;
  const int t   = threadIdx.x;
  const float scale = 1.4426950408889634f / temp[0];
  const int segbase = seg * SEG;
  const float4* rp4 = reinterpret_cast<const float4*>(logits + (size_t)row * V + segbase);
  const uint32_t cb42 = (uint32_t)row * (uint32_t)V + (uint32_t)segbase
                      + (uint32_t)(t * 4) + 42u;

  float best = -INFINITY;
  int bestJ = 0;

  // pairs of j-groups: 8 interleaved threefry chains per batch
#pragma unroll
  for (int jb = 0; jb + 2 <= J; jb += 2) {
    const float4 L0 = rp4[jb * TPB + t];
    const float4 L1 = rp4[(jb + 1) * TPB + t];
    uint32_t c[8], bits[8];
#pragma unroll
    for (int k = 0; k < 4; ++k) {
      c[k]     = cb42 + (uint32_t)(jb * TPB * 4 + k);
      c[4 + k] = cb42 + (uint32_t)((jb + 1) * TPB * 4 + k);
    }
    threefry_xor_batch<8>(c, bits);
    const float lv[8] = {L0.x, L0.y, L0.z, L0.w, L1.x, L1.y, L1.z, L1.w};
    float v[8];
#pragma unroll
    for (int i = 0; i < 8; ++i) v[i] = gval(bits[i], lv[i], scale);
    const float m0 = fmaxf(fmaxf(v[0], v[1]), fmaxf(v[2], v[3]));
    const float m1 = fmaxf(fmaxf(v[4], v[5]), fmaxf(v[6], v[7]));
    if (m0 > best) { best = m0; bestJ = jb; }       // strict >: earliest group wins ties
    if (m1 > best) { best = m1; bestJ = jb + 1; }
  }
  if constexpr (J & 1) {               // tail group of 4
    constexpr int j = J - 1;
    const float4 L0 = rp4[j * TPB + t];
    uint32_t c[4], bits[4];
#pragma unroll
    for (int k = 0; k < 4; ++k) c[k] = cb42 + (uint32_t)(j * TPB * 4 + k);
    threefry_xor_batch<4>(c, bits);
    const float lv[4] = {L0.x, L0.y, L0.z, L0.w};
    float m = -INFINITY;
#pragma unroll
    for (int i = 0; i < 4; ++i) m = fmaxf(m, gval(bits[i], lv[i], scale));
    if (m > best) { best = m; bestJ = j; }
  }

  // recover k within the winning group by exact recompute (bit-identical ops)
  {
    uint32_t c[4], bits[4];
#pragma unroll
    for (int k = 0; k < 4; ++k) c[k] = cb42 + (uint32_t)(bestJ * (TPB * 4) + k);
    threefry_xor_batch<4>(c, bits);
    const float4 L = rp4[bestJ * TPB + t];
    const float r0 = gval(bits[0], L.x, scale);
    const float r1 = gval(bits[1], L.y, scale);
    const float r2 = gval(bits[2], L.z, scale);
    const int kk = (r0 == best) ? 0 : (r1 == best) ? 1 : (r2 == best) ? 2 : 3;
    const int bestIdx = segbase + bestJ * (TPB * 4) + (t << 2) + kk;

    // wave-level argmax (64 lanes), lower index wins ties
    float bv = best; int bi = bestIdx;
#pragma unroll
    for (int off = 32; off > 0; off >>= 1) {
      const float ov = __shfl_down(bv, off);
      const int   oi = __shfl_down(bi, off);
      if (ov > bv || (ov == bv && oi < bi)) { bv = ov; bi = oi; }
    }

    __shared__ float sv[TPB / 64];
    __shared__ int   si[TPB / 64];
    const int wid = t >> 6;
    if ((t & 63) == 0) { sv[wid] = bv; si[wid] = bi; }
    __syncthreads();
    if (t == 0) {
      float fv = sv[0]; int fi = si[0];
#pragma unroll
      for (int w = 1; w < TPB / 64; ++w) {
        if (sv[w] > fv || (sv[w] == fv && si[w] < fi)) { fv = sv[w]; fi = si[w]; }
      }
      ws[b] = make_float2(fv, __int_as_float(fi));
    }
  }
}

template <int SPLIT>
__global__ __launch_bounds__(64) void CategoricalSampler_stage2(
    const float2* __restrict__ ws, int* __restrict__ out) {
  const int r = blockIdx.x;            // one wave per row
  const int l = threadIdx.x;
  float best = -INFINITY;
  int bestIdx = 0x7FFFFFFF;
  if (l < SPLIT) {
    const float2 p = ws[r * SPLIT + l];
    best = p.x; bestIdx = __float_as_int(p.y);
  }
#pragma unroll
  for (int off = 32; off > 0; off >>= 1) {
    const float ov = __shfl_down(best, off);
    const int   oi = __shfl_down(bestIdx, off);
    if (ov > best || (ov == best && oi < bestIdx)) { best = ov; bestIdx = oi; }
  }
  if (l == 0) out[r] = bestIdx;
}

extern "C" void kernel_launch(void* const* d_in, const int* in_sizes, int n_in,
                              void* d_out, int out_size, void* d_ws, size_t ws_size,
                              hipStream_t stream) {
  const float* logits = (const float*)d_in[0];
  const float* temp   = (const float*)d_in[1];
  int* out = (int*)d_out;
  float2* ws = (float2*)d_ws;
  if (ws_size >= (size_t)NROWS * SPLITQ * sizeof(float2)) {
    CategoricalSampler_stage1<SPLITQ><<<NROWS * SPLITQ, TPB, 0, stream>>>(logits, temp, ws);
    CategoricalSampler_stage2<SPLITQ><<<NROWS, 64, 0, stream>>>(ws, out);
  } else {
    CategoricalSampler_stage1<5><<<NROWS * 5, TPB, 0, stream>>>(logits, temp, ws);
    CategoricalSampler_stage2<5><<<NROWS, 64, 0, stream>>>(ws, out);
  }
}

// Round 10
// 67.696 us; speedup vs baseline: 1.1474x; 1.1474x over previous
//
#include <hip/hip_runtime.h>
#include <stdint.h>
#include <math.h>

// CategoricalSampler: argmax_v( logits[b,s,v]*(log2e/T) + g2(v) ), g2 = -log2(-log2 u),
// u from JAX threefry2x32-20 partitionable path: bits[i] = x0^x1, key=(0,42), ctr=(0, i).
// Bit-scheme verified R2; value path verified R3/R5-R9 (absmax=0).
//
// R4 lesson: direct __log2f(u) only — no cancellation forms.
// R8/R9 lessons: compiler re-sinks prefetch and serializes hand-batched chains (VGPR
// pinned ~16-20); only instruction REMOVAL pays (law: -1 inst/elem ~ -0.77us).
// R10: candidate filter on RAW BITS — u >= tau  <=>  bits >= B0 (u uniform in bits>>9).
// Skipped elems have val <= Lmax*scale + G2TAU; stage2 checks the row winner beats that
// bound (P(fail) ~ 1e-7/row) and otherwise re-scans the row exactly. Saves the whole
// value path (2 logs!) on ~77% of elements.

constexpr int V = 128000;
constexpr int NROWS = 256;       // B*S
constexpr int TPB = 256;
constexpr int SPLITQ = 25;       // grid 6400 -> 8 blocks/CU; SEG=5120, J=5

// tau = 0.996: mt = ceil(0.996*2^23) = 8355054, B0 = mt<<9. Skipped: u <= 0.99599993
// -> g2 <= 7.4342. Bound constant with margin:
constexpr uint32_t B0 = 8355054u << 9;   // 4,277,787,648
#define G2TAU 7.44f

__device__ __forceinline__ uint32_t rotl_(uint32_t x, uint32_t r) {
#if __has_builtin(__builtin_rotateleft32)
  return __builtin_rotateleft32(x, r);   // fshl -> single v_alignbit_b32
#else
  return (x << r) | (x >> (32u - r));
#endif
}

// Threefry-2x32-20, key (0,42), counter (0, ctr). Input c = ctr + 42 (ks1 pre-added).
// ks0=0, ks1=42, ks2=0x1BD11BDA^42=0x1BD11BF0. Round-1 mov folded: x0_r1 = c.
__device__ __forceinline__ uint32_t threefry_xor_pre(uint32_t c) {
  uint32_t x1 = rotl_(c, 13) ^ c;       // round 1 (x0 = 0 + c)
  uint32_t x0 = c + x1;                 // round 2
  x1 = rotl_(x1, 15) ^ x0;
  x0 += x1; x1 = rotl_(x1, 26) ^ x0;
  x0 += x1; x1 = rotl_(x1,  6) ^ x0;
  x1 += 0x1BD11BF1u; x0 = x0 + 42u + x1;         // inject1 (ks1 | ks2+1)
  x1 = rotl_(x1, 17) ^ x0;
  x0 += x1; x1 = rotl_(x1, 29) ^ x0;
  x0 += x1; x1 = rotl_(x1, 16) ^ x0;
  x0 += x1; x1 = rotl_(x1, 24) ^ x0;
  x1 += 2u; x0 = x0 + 0x1BD11BF0u + x1;          // inject2 (ks2 | ks0+2)
  x1 = rotl_(x1, 13) ^ x0;
  x0 += x1; x1 = rotl_(x1, 15) ^ x0;
  x0 += x1; x1 = rotl_(x1, 26) ^ x0;
  x0 += x1; x1 = rotl_(x1,  6) ^ x0;
  x1 += 45u; x0 += x1;                           // inject3 (ks0=0 | ks1+3)
  x1 = rotl_(x1, 17) ^ x0;
  x0 += x1; x1 = rotl_(x1, 29) ^ x0;
  x0 += x1; x1 = rotl_(x1, 16) ^ x0;
  x0 += x1; x1 = rotl_(x1, 24) ^ x0;
  x1 += 0x1BD11BF4u; x0 = x0 + 42u + x1;         // inject4 (ks1 | ks2+4)
  x1 = rotl_(x1, 13) ^ x0;
  x0 += x1; x1 = rotl_(x1, 15) ^ x0;
  x0 += x1; x1 = rotl_(x1, 26) ^ x0;
  x0 += x1; x1 = rotl_(x1,  6) ^ x0;
  return (x0 + 0x1BD11BF0u) ^ (x1 + 5u);         // inject5 (ks2 | ks0+5) folded
}

__device__ __forceinline__ uint32_t mant_pack(uint32_t bits) {
#if __has_builtin(__builtin_amdgcn_alignbit)
  return __builtin_amdgcn_alignbit(127u, bits, 9u);  // (bits>>9)|0x3f800000
#else
  return (bits >> 9) | 0x3f800000u;
#endif
}

__device__ __forceinline__ float gval(uint32_t bits, float l, float scale) {
  const float u  = __uint_as_float(mant_pack(bits)) - 1.0f;  // [0,1); 0 -> -inf, loses
  const float s1 = __log2f(u);
  const float s2 = __log2f(-s1);          // g2 = -s2 (neg folds to VOP3 modifier)
  return fmaf(l, scale, -s2);
}

template <int SPLIT>
__global__ __launch_bounds__(TPB) void CategoricalSampler_stage1(
    const float* __restrict__ logits, const float* __restrict__ temp,
    float2* __restrict__ ws1, float* __restrict__ wsl) {
  constexpr int SEG = V / SPLIT;
  constexpr int J = SEG / (TPB * 4);   // exact by construction
  const int b   = blockIdx.x;
  const int row = b / SPLIT;
  const int seg = b - row * SPLIT;
  const int t   = threadIdx.x;
  const float scale = 1.4426950408889634f / temp[0];
  const int segbase = seg * SEG;
  const float4* rp4 = reinterpret_cast<const float4*>(logits + (size_t)row * V + segbase);
  const uint32_t cb42 = (uint32_t)row * (uint32_t)V + (uint32_t)segbase
                      + (uint32_t)(t * 4) + 42u;

  float best = -INFINITY;
  int bestCode = 0;
  float lmax = -INFINITY;

#pragma unroll
  for (int j = 0; j < J; ++j) {
    const float4 L = rp4[j * TPB + t];
    lmax = fmaxf(lmax, fmaxf(fmaxf(L.x, L.y), fmaxf(L.z, L.w)));
    const uint32_t c0 = cb42 + (uint32_t)(j * TPB * 4);
#pragma unroll
    for (int k = 0; k < 4; ++k) {
      const uint32_t bits = threefry_xor_pre(c0 + (uint32_t)k);
      if (bits >= B0) {                        // candidate: u >= ~0.996 (rare, ~0.4%)
        const float lk = (k == 0) ? L.x : (k == 1) ? L.y : (k == 2) ? L.z : L.w;
        const float val = gval(bits, lk, scale);
        if (val > best) { best = val; bestCode = j * 4 + k; }
      }
    }
  }

  // reconstruct global index: v = segbase + j*TPB*4 + t*4 + k
  int bestIdx = segbase + (bestCode >> 2) * (TPB * 4) + (t << 2) + (bestCode & 3);

  // wave reduce: max val (earliest index on ties) and max logit
#pragma unroll
  for (int off = 32; off > 0; off >>= 1) {
    const float ov = __shfl_down(best, off);
    const int   oi = __shfl_down(bestIdx, off);
    const float ol = __shfl_down(lmax, off);
    if (ov > best || (ov == best && oi < bestIdx)) { best = ov; bestIdx = oi; }
    lmax = fmaxf(lmax, ol);
  }

  __shared__ float sv[TPB / 64];
  __shared__ int   si[TPB / 64];
  __shared__ float sl[TPB / 64];
  const int wid = t >> 6;
  if ((t & 63) == 0) { sv[wid] = best; si[wid] = bestIdx; sl[wid] = lmax; }
  __syncthreads();
  if (t == 0) {
    float fv = sv[0]; int fi = si[0]; float fl = sl[0];
#pragma unroll
    for (int w = 1; w < TPB / 64; ++w) {
      if (sv[w] > fv || (sv[w] == fv && si[w] < fi)) { fv = sv[w]; fi = si[w]; }
      fl = fmaxf(fl, sl[w]);
    }
    ws1[b] = make_float2(fv, __int_as_float(fi));
    wsl[b] = fl;
  }
}

// Stage 2: per row, combine segment results; verify the candidate winner beats the
// skip-bound; on the (~never) failure, re-scan the whole row exactly in this wave.
template <int SPLIT>
__global__ __launch_bounds__(64) void CategoricalSampler_stage2(
    const float2* __restrict__ ws1, const float* __restrict__ wsl,
    const float* __restrict__ logits, const float* __restrict__ temp,
    int* __restrict__ out) {
  const int r = blockIdx.x;
  const int l = threadIdx.x;
  const float scale = 1.4426950408889634f / temp[0];
  float best = -INFINITY; int bestIdx = 0x7FFFFFFF; float lmax = -INFINITY;
  if (l < SPLIT) {
    const float2 p = ws1[r * SPLIT + l];
    best = p.x; bestIdx = __float_as_int(p.y);
    lmax = wsl[r * SPLIT + l];
  }
#pragma unroll
  for (int off = 32; off > 0; off >>= 1) {
    const float ov = __shfl_down(best, off);
    const int   oi = __shfl_down(bestIdx, off);
    const float ol = __shfl_down(lmax, off);
    if (ov > best || (ov == best && oi < bestIdx)) { best = ov; bestIdx = oi; }
    lmax = fmaxf(lmax, ol);
  }
  // lane 0 holds row results; broadcast
  best = __shfl(best, 0); bestIdx = __shfl(bestIdx, 0); lmax = __shfl(lmax, 0);
  const float bound = fmaf(lmax, scale, G2TAU);   // upper bound on any skipped val
  if (best >= bound) {
    if (l == 0) out[r] = bestIdx;
    return;
  }
  // Fallback (probability ~1e-7/row): exact full-row scan by this wave.
  const uint32_t cb42 = (uint32_t)r * (uint32_t)V + 42u;
  const float* rowp = logits + (size_t)r * V;
  float fb = -INFINITY; int fi = 0;
  for (int v = l; v < V; v += 64) {              // coalesced, ascending per lane
    const uint32_t bits = threefry_xor_pre(cb42 + (uint32_t)v);
    const float val = gval(bits, rowp[v], scale);
    if (val > fb) { fb = val; fi = v; }
  }
#pragma unroll
  for (int off = 32; off > 0; off >>= 1) {
    const float ov = __shfl_down(fb, off);
    const int   oi = __shfl_down(fi, off);
    if (ov > fb || (ov == fb && oi < fi)) { fb = ov; fi = oi; }
  }
  if (l == 0) out[r] = fi;
}

extern "C" void kernel_launch(void* const* d_in, const int* in_sizes, int n_in,
                              void* d_out, int out_size, void* d_ws, size_t ws_size,
                              hipStream_t stream) {
  const float* logits = (const float*)d_in[0];
  const float* temp   = (const float*)d_in[1];
  int* out = (int*)d_out;
  if (ws_size >= (size_t)NROWS * SPLITQ * (sizeof(float2) + sizeof(float))) {
    float2* ws1 = (float2*)d_ws;
    float*  wsl = (float*)(ws1 + NROWS * SPLITQ);
    CategoricalSampler_stage1<SPLITQ><<<NROWS * SPLITQ, TPB, 0, stream>>>(logits, temp, ws1, wsl);
    CategoricalSampler_stage2<SPLITQ><<<NROWS, 64, 0, stream>>>(ws1, wsl, logits, temp, out);
  } else {
    float2* ws1 = (float2*)d_ws;
    float*  wsl = (float*)(ws1 + NROWS * 5);
    CategoricalSampler_stage1<5><<<NROWS * 5, TPB, 0, stream>>>(logits, temp, ws1, wsl);
    CategoricalSampler_stage2<5><<<NROWS, 64, 0, stream>>>(ws1, wsl, logits, temp, out);
  }
}

// Round 11
// 62.151 us; speedup vs baseline: 1.2498x; 1.0892x over previous
//
#include <hip/hip_runtime.h>
#include <stdint.h>
#include <math.h>

// CategoricalSampler: argmax_v( logits[b,s,v]*(log2e/T) + g2(v) ), g2 = -log2(-log2 u),
// u from JAX threefry2x32-20 partitionable path: bits[i] = x0^x1, key=(0,42), ctr=(0, i).
// Bit-scheme verified R2; value path verified R3/R5-R10 (absmax=0).
//
// R4: no cancellation forms in the log path. R8/R9: compiler ignores source-level
// scheduling; only instruction removal pays. R10: raw-bits candidate filter (u>=tau
// <=> bits>=B0) + stage2 bound check & exact fallback — verified passing.
// R11: (a) FORCED 1-inst rotates via inline-asm v_alignbit_b32 (tests the fshl-lowering
// bloat hypothesis); (b) uniform grid: SPLIT=5 -> 1280 blocks = exactly 5/CU, single
// residency round, no ragged tail (R10 ran rounds {8,8,8,1} per CU).

constexpr int V = 128000;
constexpr int NROWS = 256;       // B*S
constexpr int TPB = 256;
constexpr int SPLIT = 5;         // grid 1280 = 5 blocks/CU exactly (20 waves/CU steady)
constexpr int SEG = V / SPLIT;   // 25600
constexpr int J = SEG / (TPB * 4);  // 25 exact

// tau ~ 0.996: B0 = ceil(0.996*2^23)<<9. Skipped elems: g2 <= 7.4342 < G2TAU.
constexpr uint32_t B0 = 8355054u << 9;
#define G2TAU 7.44f

// Forced single-instruction rotate: rotl(x,r) == v_alignbit_b32(x, x, 32-r).
// Shift amounts {19,17,6,26,15,3,16,8} are all inline constants (<=64) — VOP3-legal.
template <uint32_t R>
__device__ __forceinline__ uint32_t rotl_(uint32_t x) {
  uint32_t d;
  asm("v_alignbit_b32 %0, %1, %1, %2" : "=v"(d) : "v"(x), "n"(32u - R));
  return d;
}

// Threefry-2x32-20, key (0,42), counter (0, ctr). Input c = ctr + 42 (ks1 pre-added).
// ks0=0, ks1=42, ks2=0x1BD11BDA^42=0x1BD11BF0. Round-1 mov folded: x0_r1 = c.
__device__ __forceinline__ uint32_t threefry_xor_pre(uint32_t c) {
  uint32_t x1 = rotl_<13>(c) ^ c;       // round 1 (x0 = 0 + c)
  uint32_t x0 = c + x1;                 // round 2
  x1 = rotl_<15>(x1) ^ x0;
  x0 += x1; x1 = rotl_<26>(x1) ^ x0;
  x0 += x1; x1 = rotl_< 6>(x1) ^ x0;
  x1 += 0x1BD11BF1u; x0 = x0 + 42u + x1;         // inject1 (ks1 | ks2+1)
  x1 = rotl_<17>(x1) ^ x0;
  x0 += x1; x1 = rotl_<29>(x1) ^ x0;
  x0 += x1; x1 = rotl_<16>(x1) ^ x0;
  x0 += x1; x1 = rotl_<24>(x1) ^ x0;
  x1 += 2u; x0 = x0 + 0x1BD11BF0u + x1;          // inject2 (ks2 | ks0+2)
  x1 = rotl_<13>(x1) ^ x0;
  x0 += x1; x1 = rotl_<15>(x1) ^ x0;
  x0 += x1; x1 = rotl_<26>(x1) ^ x0;
  x0 += x1; x1 = rotl_< 6>(x1) ^ x0;
  x1 += 45u; x0 += x1;                           // inject3 (ks0=0 | ks1+3)
  x1 = rotl_<17>(x1) ^ x0;
  x0 += x1; x1 = rotl_<29>(x1) ^ x0;
  x0 += x1; x1 = rotl_<16>(x1) ^ x0;
  x0 += x1; x1 = rotl_<24>(x1) ^ x0;
  x1 += 0x1BD11BF4u; x0 = x0 + 42u + x1;         // inject4 (ks1 | ks2+4)
  x1 = rotl_<13>(x1) ^ x0;
  x0 += x1; x1 = rotl_<15>(x1) ^ x0;
  x0 += x1; x1 = rotl_<26>(x1) ^ x0;
  x0 += x1; x1 = rotl_< 6>(x1) ^ x0;
  return (x0 + 0x1BD11BF0u) ^ (x1 + 5u);         // inject5 (ks2 | ks0+5) folded
}

__device__ __forceinline__ uint32_t mant_pack(uint32_t bits) {
#if __has_builtin(__builtin_amdgcn_alignbit)
  return __builtin_amdgcn_alignbit(127u, bits, 9u);  // (bits>>9)|0x3f800000
#else
  return (bits >> 9) | 0x3f800000u;
#endif
}

__device__ __forceinline__ float gval(uint32_t bits, float l, float scale) {
  const float u  = __uint_as_float(mant_pack(bits)) - 1.0f;  // [0,1); 0 -> -inf, loses
  const float s1 = __log2f(u);
  const float s2 = __log2f(-s1);          // g2 = -s2 (neg folds to VOP3 modifier)
  return fmaf(l, scale, -s2);
}

__global__ __launch_bounds__(TPB) void CategoricalSampler_stage1(
    const float* __restrict__ logits, const float* __restrict__ temp,
    float2* __restrict__ ws1, float* __restrict__ wsl) {
  const int b   = blockIdx.x;
  const int row = b / SPLIT;
  const int seg = b - row * SPLIT;
  const int t   = threadIdx.x;
  const float scale = 1.4426950408889634f / temp[0];
  const int segbase = seg * SEG;
  const float4* rp4 = reinterpret_cast<const float4*>(logits + (size_t)row * V + segbase);
  const uint32_t cb42 = (uint32_t)row * (uint32_t)V + (uint32_t)segbase
                      + (uint32_t)(t * 4) + 42u;

  float best = -INFINITY;
  int bestCode = 0;
  float lmax = -INFINITY;

#pragma unroll 5
  for (int j = 0; j < J; ++j) {
    const float4 L = rp4[j * TPB + t];
    lmax = fmaxf(lmax, fmaxf(fmaxf(L.x, L.y), fmaxf(L.z, L.w)));
    const uint32_t c0 = cb42 + (uint32_t)(j * TPB * 4);
#pragma unroll
    for (int k = 0; k < 4; ++k) {
      const uint32_t bits = threefry_xor_pre(c0 + (uint32_t)k);
      if (bits >= B0) {                        // candidate: u >= ~0.996
        const float lk = (k == 0) ? L.x : (k == 1) ? L.y : (k == 2) ? L.z : L.w;
        const float val = gval(bits, lk, scale);
        if (val > best) { best = val; bestCode = j * 4 + k; }
      }
    }
  }

  // reconstruct global index: v = segbase + j*TPB*4 + t*4 + k
  int bestIdx = segbase + (bestCode >> 2) * (TPB * 4) + (t << 2) + (bestCode & 3);

  // wave reduce: max val (earliest index on ties) and max logit
#pragma unroll
  for (int off = 32; off > 0; off >>= 1) {
    const float ov = __shfl_down(best, off);
    const int   oi = __shfl_down(bestIdx, off);
    const float ol = __shfl_down(lmax, off);
    if (ov > best || (ov == best && oi < bestIdx)) { best = ov; bestIdx = oi; }
    lmax = fmaxf(lmax, ol);
  }

  __shared__ float sv[TPB / 64];
  __shared__ int   si[TPB / 64];
  __shared__ float sl[TPB / 64];
  const int wid = t >> 6;
  if ((t & 63) == 0) { sv[wid] = best; si[wid] = bestIdx; sl[wid] = lmax; }
  __syncthreads();
  if (t == 0) {
    float fv = sv[0]; int fi = si[0]; float fl = sl[0];
#pragma unroll
    for (int w = 1; w < TPB / 64; ++w) {
      if (sv[w] > fv || (sv[w] == fv && si[w] < fi)) { fv = sv[w]; fi = si[w]; }
      fl = fmaxf(fl, sl[w]);
    }
    ws1[b] = make_float2(fv, __int_as_float(fi));
    wsl[b] = fl;
  }
}

// Stage 2: combine segments; verify winner beats the skip-bound (P(fail) ~1e-6/row,
// and R10 passed on this fixed dataset); exact full-row re-scan on failure.
__global__ __launch_bounds__(64) void CategoricalSampler_stage2(
    const float2* __restrict__ ws1, const float* __restrict__ wsl,
    const float* __restrict__ logits, const float* __restrict__ temp,
    int* __restrict__ out) {
  const int r = blockIdx.x;
  const int l = threadIdx.x;
  const float scale = 1.4426950408889634f / temp[0];
  float best = -INFINITY; int bestIdx = 0x7FFFFFFF; float lmax = -INFINITY;
  if (l < SPLIT) {
    const float2 p = ws1[r * SPLIT + l];
    best = p.x; bestIdx = __float_as_int(p.y);
    lmax = wsl[r * SPLIT + l];
  }
#pragma unroll
  for (int off = 32; off > 0; off >>= 1) {
    const float ov = __shfl_down(best, off);
    const int   oi = __shfl_down(bestIdx, off);
    const float ol = __shfl_down(lmax, off);
    if (ov > best || (ov == best && oi < bestIdx)) { best = ov; bestIdx = oi; }
    lmax = fmaxf(lmax, ol);
  }
  best = __shfl(best, 0); bestIdx = __shfl(bestIdx, 0); lmax = __shfl(lmax, 0);
  const float bound = fmaf(lmax, scale, G2TAU);   // upper bound on any skipped val
  if (best >= bound) {
    if (l == 0) out[r] = bestIdx;
    return;
  }
  // Fallback: exact full-row scan by this wave (bit-identical math).
  const uint32_t cb42 = (uint32_t)r * (uint32_t)V + 42u;
  const float* rowp = logits + (size_t)r * V;
  float fb = -INFINITY; int fi = 0;
  for (int v = l; v < V; v += 64) {
    const uint32_t bits = threefry_xor_pre(cb42 + (uint32_t)v);
    const float val = gval(bits, rowp[v], scale);
    if (val > fb) { fb = val; fi = v; }
  }
#pragma unroll
  for (int off = 32; off > 0; off >>= 1) {
    const float ov = __shfl_down(fb, off);
    const int   oi = __shfl_down(fi, off);
    if (ov > fb || (ov == fb && oi < fi)) { fb = ov; fi = oi; }
  }
  if (l == 0) out[r] = fi;
}

extern "C" void kernel_launch(void* const* d_in, const int* in_sizes, int n_in,
                              void* d_out, int out_size, void* d_ws, size_t ws_size,
                              hipStream_t stream) {
  const float* logits = (const float*)d_in[0];
  const float* temp   = (const float*)d_in[1];
  int* out = (int*)d_out;
  float2* ws1 = (float2*)d_ws;                   // 1280 float2
  float*  wsl = (float*)(ws1 + NROWS * SPLIT);   // 1280 float  (total 15.4 KB)
  CategoricalSampler_stage1<<<NROWS * SPLIT, TPB, 0, stream>>>(logits, temp, ws1, wsl);
  CategoricalSampler_stage2<<<NROWS, 64, 0, stream>>>(ws1, wsl, logits, temp, out);
}